// Round 1
// baseline (194.704 us; speedup 1.0000x reference)
//
#include <hip/hip_runtime.h>
#include <hip/hip_bf16.h>
#include <hip/hip_fp16.h>

// Problem constants (fixed by the reference)
#define N_GENES_MAX 5000
#define N_ELEM_MAX  4000000
#define PARAMS_PER_GENE 445

// Packed knot (8B): {loc f32; y = (h f16 << 16) | (cdf-loc) f16}.
// Two-pass stage split (R9): pass A touches only g_k0 (5.0 MB ~ per-XCD L2),
// pass B touches g_k1+g_k2 (3.75 MB, fully L2-resident). Midstate between
// passes: uint2 {x' f32, (gene << 16) | lad0 f16} — 8B/elem coalesced.
// R10: pair-load (one dwordx4 fetches knots b,b+1) + 4 elems/thread ILP.
__device__ uint2 g_k0[(size_t)N_GENES_MAX * 128];
__device__ uint2 g_k1[(size_t)N_GENES_MAX * 64];
__device__ uint2 g_k2[(size_t)N_GENES_MAX * 32];
__device__ uint2 g_mid[N_ELEM_MAX];

static __device__ __forceinline__ unsigned f2h(float f) {
    union { __half h; unsigned short u; } c;
    c.h = __float2half_rn(f);
    return (unsigned)c.u;
}
static __device__ __forceinline__ float h2f(unsigned u) {
    union { unsigned short u; __half h; } c;
    c.u = (unsigned short)u;
    return __half2float(c.h);
}

// ---- wave-level primitives (64 lanes) ----
static __device__ __forceinline__ float wscan_incl(float v) {
    const int lane = threadIdx.x & 63;
    #pragma unroll
    for (int off = 1; off < 64; off <<= 1) {
        float u = __shfl_up(v, off, 64);
        if (lane >= off) v += u;
    }
    return v;
}
static __device__ __forceinline__ float wmax64(float v) {
    #pragma unroll
    for (int off = 32; off > 0; off >>= 1) v = fmaxf(v, __shfl_xor(v, off, 64));
    return v;
}
static __device__ __forceinline__ float wsum64(float v) {
    #pragma unroll
    for (int off = 32; off > 0; off >>= 1) v += __shfl_xor(v, off, 64);
    return v;
}

// ---------------------------------------------------------------------------
// Kernel 1: build per-(gene,stage) knots. grid=(G,3), block=128 (2 waves).
// (R8-verified: wave-shuffle scans + 2-element LDS cross-wave combine.)
// ---------------------------------------------------------------------------
__global__ void build_knots(const float* __restrict__ params) {
    const int g = blockIdx.x;
    const int t = blockIdx.y;
    const int ns[3]   = {128, 64, 32};
    const int poff[3] = {0, 255, 382};

    const int n = ns[t];
    const int m = n - 1;
    const float* ph = params + (size_t)g * PARAMS_PER_GENE + poff[t];
    const float* pw = ph + n;

    __shared__ float s2[2];
    __shared__ float s_scan[128];
    __shared__ float s_h[129];
    __shared__ float s_loc[128];
    __shared__ float s_cdf[128];

    const int tid  = threadIdx.x;
    const int lane = tid & 63;
    const int wv   = tid >> 6;

    const float uw = (tid < m) ? pw[tid] : -1e30f;
    float vmax = wmax64(uw);
    if (lane == 0) s2[wv] = vmax;
    __syncthreads();
    const float mx = fmaxf(s2[0], s2[1]);
    __syncthreads();

    const float e = (tid < m) ? __expf(uw - mx) : 0.0f;

    float sc = wscan_incl(e);
    if (lane == 63) s2[wv] = sc;
    __syncthreads();
    if (wv == 1) sc += s2[0];
    s_scan[tid] = sc;
    __syncthreads();

    const float S = s_scan[m - 1];
    const float invS = 1.0f / S;
    if (tid == 0) s_loc[0] = 0.0f;
    if (tid < m) s_loc[tid + 1] = (tid == m - 1) ? 1.0f : s_scan[tid] * invS;
    const float w_i = e * invS;

    const float eh = (tid < n) ? __expf(ph[tid]) : 0.0f;
    s_h[tid] = eh;
    if (tid == 0) s_h[128] = 0.0f;
    __syncthreads();

    const float term = (tid < m) ? 0.5f * (s_h[tid] + s_h[tid + 1]) * w_i : 0.0f;
    float ts = wsum64(term);
    if (lane == 0) s2[wv] = ts;
    __syncthreads();
    const float area = s2[0] + s2[1];
    __syncthreads();

    const float ia = 1.0f / area;
    const float hgt = eh * ia;

    float c = wscan_incl(term * ia);
    if (lane == 63) s2[wv] = c;
    __syncthreads();
    if (wv == 1) c += s2[0];
    s_scan[tid] = c;
    __syncthreads();

    if (tid == 0) s_cdf[0] = 0.0f;
    if (tid < m) s_cdf[tid + 1] = (tid == m - 1) ? 1.0f : s_scan[tid];
    __syncthreads();

    if (tid < n) {
        const float loc = s_loc[tid];
        uint2 kt;
        kt.x = __float_as_uint(loc);
        kt.y = (f2h(hgt) << 16) | f2h(s_cdf[tid] - loc);
        if (t == 0)      g_k0[(size_t)g * 128 + tid] = kt;
        else if (t == 1) g_k1[(size_t)g * 64 + tid] = kt;
        else             g_k2[(size_t)g * 32 + tid] = kt;
    }
}

typedef float fvec2 __attribute__((ext_vector_type(2)));
typedef float fvec4 __attribute__((ext_vector_type(4)));
typedef int   ivec4 __attribute__((ext_vector_type(4)));
typedef unsigned uvec4 __attribute__((ext_vector_type(4)));
// 8B-aligned 16B vector: lets one global_load_dwordx4 fetch knot pair
// kn[b],kn[b+1] (HW only needs dword alignment for global vector loads).
typedef uvec4 uvec4_a8 __attribute__((aligned(8)));

static __device__ __forceinline__ uvec4 ldpair(const uint2* __restrict__ p) {
    return *(const uvec4_a8*)p;
}

// ---------------------------------------------------------------------------
// Stage evaluation from packed knots. One 16B pair-load per probe (R10):
// knots b and b+1 are adjacent 8B records -> single dwordx4 gather.
// ---------------------------------------------------------------------------
template <int K>
static __device__ __forceinline__ void stage(const uint2* __restrict__ kn,
                                             float& x, float& lad) {
    int b = (int)(x * (float)(K - 1));
    b = (b < 0) ? 0 : ((b > K - 2) ? K - 2 : b);
    uvec4 p = ldpair(kn + b);
    float l0 = __uint_as_float(p.x);
    float l1 = __uint_as_float(p.z);
    while (b > 0 && l0 > x) {
        --b;
        p = ldpair(kn + b);
        l0 = __uint_as_float(p.x);
        l1 = __uint_as_float(p.z);
    }
    while (b < K - 2 && l1 <= x) {
        ++b;
        p = ldpair(kn + b);
        l0 = __uint_as_float(p.x);
        l1 = __uint_as_float(p.z);
    }
    const float lh = h2f(p.y >> 16);
    const float rh = h2f(p.w >> 16);
    const float lc = l0 + h2f(p.y & 0xffffu);
    const float w  = l1 - l0;
    const float alpha = (x - l0) / w;
    float o = (0.5f * (rh - lh) * w) * alpha * alpha + (lh * w) * alpha + lc;
    o = fminf(fmaxf(o, 0.0f), 1.0f);
    lad += __logf(alpha * (rh - lh) + lh);
    x = o;
}

// ---------------------------------------------------------------------------
// Kernel 2a: pass A — stage0 only (table 5.0 MB). 4 elems/thread (R10).
// ---------------------------------------------------------------------------
__global__ void spline_evalA(const float* __restrict__ x_in,
                             const int* __restrict__ gix, int N) {
    const int i = blockIdx.x * blockDim.x + threadIdx.x;
    const long i4 = (long)i * 4;
    if (i4 + 3 < N) {
        const fvec4 xv = __builtin_nontemporal_load((const fvec4*)(x_in + i4));
        const ivec4 gv = __builtin_nontemporal_load((const ivec4*)(gix + i4));
        float x0 = xv.x, x1 = xv.y, x2 = xv.z, x3 = xv.w;
        float l0 = 0.0f, l1 = 0.0f, l2 = 0.0f, l3 = 0.0f;
        stage<128>(g_k0 + (size_t)gv.x * 128, x0, l0);
        stage<128>(g_k0 + (size_t)gv.y * 128, x1, l1);
        stage<128>(g_k0 + (size_t)gv.z * 128, x2, l2);
        stage<128>(g_k0 + (size_t)gv.w * 128, x3, l3);
        uvec4 m0, m1;
        m0.x = __float_as_uint(x0);
        m0.y = ((unsigned)gv.x << 16) | f2h(l0);
        m0.z = __float_as_uint(x1);
        m0.w = ((unsigned)gv.y << 16) | f2h(l1);
        m1.x = __float_as_uint(x2);
        m1.y = ((unsigned)gv.z << 16) | f2h(l2);
        m1.z = __float_as_uint(x3);
        m1.w = ((unsigned)gv.w << 16) | f2h(l3);
        __builtin_nontemporal_store(m0, (uvec4*)(g_mid + i4));
        __builtin_nontemporal_store(m1, (uvec4*)(g_mid + i4 + 2));
    } else {
        for (long j = i4; j < N; ++j) {
            float x0 = x_in[j];
            float l0 = 0.0f;
            const int g = gix[j];
            stage<128>(g_k0 + (size_t)g * 128, x0, l0);
            uint2 m;
            m.x = __float_as_uint(x0);
            m.y = ((unsigned)g << 16) | f2h(l0);
            g_mid[j] = m;
        }
    }
}

// ---------------------------------------------------------------------------
// Kernel 2b: pass B — stages 1+2 (tables 3.75 MB, L2-resident). 4 elems/thr.
// ---------------------------------------------------------------------------
__global__ void spline_evalB(float* __restrict__ out, int N) {
    const int i = blockIdx.x * blockDim.x + threadIdx.x;
    const long i4 = (long)i * 4;
    if (i4 + 3 < N) {
        const uvec4 m0 = __builtin_nontemporal_load((const uvec4*)(g_mid + i4));
        const uvec4 m1 = __builtin_nontemporal_load((const uvec4*)(g_mid + i4 + 2));
        float x0 = __uint_as_float(m0.x);
        float x1 = __uint_as_float(m0.z);
        float x2 = __uint_as_float(m1.x);
        float x3 = __uint_as_float(m1.z);
        const int g0 = (int)(m0.y >> 16);
        const int g1 = (int)(m0.w >> 16);
        const int g2 = (int)(m1.y >> 16);
        const int g3 = (int)(m1.w >> 16);
        float l0 = h2f(m0.y & 0xffffu);
        float l1 = h2f(m0.w & 0xffffu);
        float l2 = h2f(m1.y & 0xffffu);
        float l3 = h2f(m1.w & 0xffffu);
        stage<64>(g_k1 + (size_t)g0 * 64, x0, l0);
        stage<64>(g_k1 + (size_t)g1 * 64, x1, l1);
        stage<64>(g_k1 + (size_t)g2 * 64, x2, l2);
        stage<64>(g_k1 + (size_t)g3 * 64, x3, l3);
        stage<32>(g_k2 + (size_t)g0 * 32, x0, l0);
        stage<32>(g_k2 + (size_t)g1 * 32, x1, l1);
        stage<32>(g_k2 + (size_t)g2 * 32, x2, l2);
        stage<32>(g_k2 + (size_t)g3 * 32, x3, l3);
        fvec4 xo; xo.x = x0; xo.y = x1; xo.z = x2; xo.w = x3;
        fvec4 lo; lo.x = l0; lo.y = l1; lo.z = l2; lo.w = l3;
        __builtin_nontemporal_store(xo, (fvec4*)(out + i4));
        __builtin_nontemporal_store(lo, (fvec4*)(out + N + i4));
    } else {
        for (long j = i4; j < N; ++j) {
            const uint2 mid = g_mid[j];
            float x0 = __uint_as_float(mid.x);
            const int g0 = (int)(mid.y >> 16);
            float l0 = h2f(mid.y & 0xffffu);
            stage<64>(g_k1 + (size_t)g0 * 64, x0, l0);
            stage<32>(g_k2 + (size_t)g0 * 32, x0, l0);
            out[j] = x0;
            out[N + j] = l0;
        }
    }
}

// ---------------------------------------------------------------------------
extern "C" void kernel_launch(void* const* d_in, const int* in_sizes, int n_in,
                              void* d_out, int out_size, void* d_ws, size_t ws_size,
                              hipStream_t stream) {
    const float* x      = (const float*)d_in[0];
    const int*   gix    = (const int*)d_in[1];
    const float* params = (const float*)d_in[2];
    float* out = (float*)d_out;

    const int N = in_sizes[0];
    const int G = in_sizes[2] / PARAMS_PER_GENE;

    build_knots<<<dim3(G, 3), 128, 0, stream>>>(params);

    const int block = 256;
    const int nq = (N + 3) / 4;
    const int grid = (nq + block - 1) / block;
    spline_evalA<<<grid, block, 0, stream>>>(x, gix, N);
    spline_evalB<<<grid, block, 0, stream>>>(out, N);
}